// Round 11
// baseline (756.845 us; speedup 1.0000x reference)
//
#include <hip/hip_runtime.h>
#include <math.h>

// ---------------------------------------------------------------------------
// HelmholtzGCN forward. R11 = R10 with single-pass k_part (global per-bucket
// cursors; no LDS histogram, one read of the edge list instead of two).
//   memset(bcnt) -> k_part -> k_build(+BN tables, zero rows) -> k_gemm1 ->
//   k_conv1 -> k_gemm2 -> k_conv2(+loss block)
// h1/h2 are dinv-prescaled in the GEMM epilogues; edge stream = plain src
// index (pad = zero-row N); convs: 4 nodes/wave, 4ch/lane, pad-8 unroll-8.
// ---------------------------------------------------------------------------

#define BN_EPS 1e-5f
#define NB_BKT 512
#define RCAP 4608      // raw per-bucket capacity (mean 4096, ~8 sigma)
#define PSTRIDE 6400   // RCAP + 256*7 max pad (pad-to-8)

typedef __attribute__((ext_vector_type(8))) short bf16x8;
typedef __attribute__((ext_vector_type(4))) float f32x4;

__device__ inline unsigned short f2b(float f) {
    unsigned u = __float_as_uint(f);
    unsigned r = (u + 0x7fffu + ((u >> 16) & 1u)) >> 16;
    return (unsigned short)r;
}
__device__ inline float b2f_lo(unsigned u) { return __uint_as_float(u << 16); }
__device__ inline float b2f_hi(unsigned u) { return __uint_as_float(u & 0xffff0000u); }
__device__ inline unsigned pk2(float a, float b) {
    return (unsigned)f2b(a) | ((unsigned)f2b(b) << 16);
}
__device__ inline float tanh_fast(float x) {
    float e = __expf(2.0f * x);
    return 1.0f - 2.0f * __builtin_amdgcn_rcpf(e + 1.0f);
}

// single-pass partition: global per-bucket cursor reservation, packed
// u32 = (dst&255)<<24 | src written straight into fixed-stride buckets.
__global__ __launch_bounds__(256) void k_part(const int* __restrict__ src,
                                              const int* __restrict__ dst, int e,
                                              unsigned* __restrict__ bcnt,
                                              unsigned* __restrict__ part) {
    int stride = gridDim.x * 1024;
    for (int base = (blockIdx.x * 256 + threadIdx.x) * 4; base < e; base += stride) {
        if (base + 3 < e) {
            int4 s = *(const int4*)&src[base];
            int4 d = *(const int4*)&dst[base];
            unsigned b0 = (unsigned)d.x >> 8, b1 = (unsigned)d.y >> 8;
            unsigned b2 = (unsigned)d.z >> 8, b3 = (unsigned)d.w >> 8;
            unsigned p0 = atomicAdd(&bcnt[b0], 1u);
            unsigned p1 = atomicAdd(&bcnt[b1], 1u);
            unsigned p2 = atomicAdd(&bcnt[b2], 1u);
            unsigned p3 = atomicAdd(&bcnt[b3], 1u);
            if (p0 < RCAP) part[b0 * RCAP + p0] = (((unsigned)d.x & 255u) << 24) | (unsigned)s.x;
            if (p1 < RCAP) part[b1 * RCAP + p1] = (((unsigned)d.y & 255u) << 24) | (unsigned)s.y;
            if (p2 < RCAP) part[b2 * RCAP + p2] = (((unsigned)d.z & 255u) << 24) | (unsigned)s.z;
            if (p3 < RCAP) part[b3 * RCAP + p3] = (((unsigned)d.w & 255u) << 24) | (unsigned)s.w;
        } else {
            for (int j = base; j < e; ++j) {
                unsigned b = (unsigned)dst[j] >> 8;
                unsigned p = atomicAdd(&bcnt[b], 1u);
                if (p < RCAP)
                    part[b * RCAP + p] = (((unsigned)dst[j] & 255u) << 24) | (unsigned)src[j];
            }
        }
    }
}

// Fused deg+scatter: per-bucket hist -> pad-8 scan -> rowinfo/dinv -> scatter
// plain src indices (pad = n, the zero row). Block 0: BN tables + zero rows.
__global__ __launch_bounds__(256) void k_build(const unsigned* __restrict__ part,
                                               const unsigned* __restrict__ bcnt,
                                               unsigned long long* __restrict__ rowinfo,
                                               float* __restrict__ dinv,
                                               unsigned* __restrict__ qs, int n,
                                               const float* __restrict__ b1,
                                               const float* __restrict__ g1,
                                               const float* __restrict__ be1,
                                               const float* __restrict__ m1,
                                               const float* __restrict__ v1,
                                               const float* __restrict__ b2p,
                                               const float* __restrict__ g2,
                                               const float* __restrict__ be2,
                                               const float* __restrict__ m2,
                                               const float* __restrict__ v2,
                                               float* __restrict__ A1,
                                               float* __restrict__ S1,
                                               float* __restrict__ A2,
                                               float* __restrict__ S2,
                                               unsigned* __restrict__ h1,
                                               unsigned* __restrict__ h2) {
    __shared__ unsigned hist[256];
    __shared__ unsigned sc[256];
    __shared__ unsigned cur[256];
    __shared__ unsigned pend[256];
    int b = blockIdx.x;
    int t = threadIdx.x;
    if (b == 0) {  // BN tables + zero pad rows (independent of shared state)
        if (t < 64) {
            float a = g1[t] * rsqrtf(v1[t] + BN_EPS);
            A1[t] = a;
            S1[t] = (b1[t] - m1[t]) * a + be1[t];
        } else if (t < 104) {
            int cc = t - 64;
            float a = g2[cc] * rsqrtf(v2[cc] + BN_EPS);
            A2[cc] = a;
            S2[cc] = (b2p[cc] - m2[cc]) * a + be2[cc];
        } else if (t < 136) {
            h1[(size_t)n * 32u + (t - 104)] = 0u;
        } else if (t < 156) {
            h2[(size_t)n * 20u + (t - 136)] = 0u;
        }
    }
    int cnt = (int)min(bcnt[b], (unsigned)RCAP);
    unsigned base = b * RCAP;
    int dst0 = b << 8;
    int nloc = min(256, n - dst0);
    hist[t] = 0;
    __syncthreads();
    for (int i = t; i < cnt; i += 256) atomicAdd(&hist[part[base + i] >> 24], 1u);
    __syncthreads();
    unsigned c = hist[t];
    unsigned pcnt = (t < nloc) ? ((c + 7u) & ~7u) : 0u;
    sc[t] = pcnt;
    __syncthreads();
    for (int off = 1; off < 256; off <<= 1) {
        unsigned a = (t >= off) ? sc[t - off] : 0u;
        __syncthreads();
        sc[t] += a;
        __syncthreads();
    }
    unsigned beg = (unsigned)b * PSTRIDE + (sc[t] - pcnt);
    if (t < nloc) {
        rowinfo[dst0 + t] = (unsigned long long)beg | ((unsigned long long)pcnt << 32);
        dinv[dst0 + t] = rsqrtf((float)(c + 1u));
    }
    cur[t] = beg;
    pend[t] = beg + pcnt;
    __syncthreads();
    for (int i = t; i < cnt; i += 256) {
        unsigned p = part[base + i];
        unsigned pos = atomicAdd(&cur[p >> 24], 1u);
        qs[pos] = p & 0xFFFFFFu;
    }
    __syncthreads();
    for (unsigned pos = cur[t]; pos < pend[t]; ++pos) qs[pos] = (unsigned)n;
}

// H1'[n+1,32 u32 pairs](bf16) = dinv[row] * (X[n,128](f32) @ W[128,64]) via MFMA.
__global__ __launch_bounds__(256) void k_gemm1(const float* __restrict__ X,
                                               const float* __restrict__ W,
                                               const float* __restrict__ dinv,
                                               unsigned* __restrict__ H, int n) {
    __shared__ short wb[4][4][64][8];
    __shared__ float cbuf[4][16][65];
    int t = threadIdx.x;
    for (int s = t; s < 1024; s += 256) {
        int l = s & 63, nt = (s >> 6) & 3, kt = s >> 8;
        int kbase = kt * 32 + ((l >> 4) << 3);
        int nn = nt * 16 + (l & 15);
        bf16x8 v;
#pragma unroll
        for (int j = 0; j < 8; ++j) v[j] = (short)f2b(W[(kbase + j) * 64 + nn]);
        *(bf16x8*)&wb[kt][nt][l][0] = v;
    }
    __syncthreads();
    int lane = t & 63, wave = t >> 6;
    int quad = lane >> 4, m = lane & 15;
    int r0 = blockIdx.x * 64 + wave * 16;
    f32x4 acc[4];
#pragma unroll
    for (int i = 0; i < 4; ++i) acc[i] = (f32x4){0.f, 0.f, 0.f, 0.f};
    int rr = min(r0 + m, n - 1);
    const float* xrow = X + (size_t)rr * 128;
#pragma unroll
    for (int kt = 0; kt < 4; ++kt) {
        int kb = kt * 32 + quad * 8;
        float4 x0 = *(const float4*)&xrow[kb];
        float4 x1 = *(const float4*)&xrow[kb + 4];
        bf16x8 af;
        af[0] = (short)f2b(x0.x); af[1] = (short)f2b(x0.y);
        af[2] = (short)f2b(x0.z); af[3] = (short)f2b(x0.w);
        af[4] = (short)f2b(x1.x); af[5] = (short)f2b(x1.y);
        af[6] = (short)f2b(x1.z); af[7] = (short)f2b(x1.w);
#pragma unroll
        for (int nt = 0; nt < 4; ++nt) {
            bf16x8 bf = *(bf16x8*)&wb[kt][nt][lane][0];
            acc[nt] = __builtin_amdgcn_mfma_f32_16x16x32_bf16(af, bf, acc[nt], 0, 0, 0);
        }
    }
#pragma unroll
    for (int nt = 0; nt < 4; ++nt)
#pragma unroll
        for (int r = 0; r < 4; ++r)
            cbuf[wave][quad * 4 + r][nt * 16 + m] = acc[nt][r];
    __syncthreads();
#pragma unroll
    for (int i = 0; i < 8; ++i) {
        int f = i * 64 + lane;
        int row = f >> 5, cp = f & 31;
        int grow = r0 + row;
        if (grow < n) {
            float dv = dinv[grow];
            H[(size_t)grow * 32 + cp] =
                pk2(dv * cbuf[wave][row][2 * cp], dv * cbuf[wave][row][2 * cp + 1]);
        }
    }
}

// H2'[n+1,20 u32 pairs](bf16) = dinv[row] * (Xb[n,64](bf16) @ W2[64,40]) via MFMA.
__global__ __launch_bounds__(256) void k_gemm2(const unsigned short* __restrict__ X,
                                               const float* __restrict__ W,
                                               const float* __restrict__ dinv,
                                               unsigned* __restrict__ H, int n) {
    __shared__ short wb[2][3][64][8];
    __shared__ float cbuf[4][16][49];
    int t = threadIdx.x;
    for (int s = t; s < 384; s += 256) {
        int l = s & 63, nt = (s >> 6) % 3, kt = s / 192;
        int kbase = kt * 32 + ((l >> 4) << 3);
        int c = nt * 16 + (l & 15);
        bf16x8 v;
#pragma unroll
        for (int j = 0; j < 8; ++j)
            v[j] = (c < 40) ? (short)f2b(W[(kbase + j) * 40 + c]) : (short)0;
        *(bf16x8*)&wb[kt][nt][l][0] = v;
    }
    __syncthreads();
    int lane = t & 63, wave = t >> 6;
    int quad = lane >> 4, m = lane & 15;
    int r0 = blockIdx.x * 64 + wave * 16;
    f32x4 acc[3];
#pragma unroll
    for (int i = 0; i < 3; ++i) acc[i] = (f32x4){0.f, 0.f, 0.f, 0.f};
    int rr = min(r0 + m, n - 1);
    const unsigned short* xrow = X + (size_t)rr * 64;
#pragma unroll
    for (int kt = 0; kt < 2; ++kt) {
        bf16x8 af = *(const bf16x8*)&xrow[kt * 32 + quad * 8];
#pragma unroll
        for (int nt = 0; nt < 3; ++nt) {
            bf16x8 bf = *(bf16x8*)&wb[kt][nt][lane][0];
            acc[nt] = __builtin_amdgcn_mfma_f32_16x16x32_bf16(af, bf, acc[nt], 0, 0, 0);
        }
    }
#pragma unroll
    for (int nt = 0; nt < 3; ++nt)
#pragma unroll
        for (int r = 0; r < 4; ++r)
            cbuf[wave][quad * 4 + r][nt * 16 + m] = acc[nt][r];
    __syncthreads();
#pragma unroll
    for (int i = 0; i < 5; ++i) {
        int f = i * 64 + lane;
        int row = f / 20, cp = f % 20;
        int grow = r0 + row;
        if (grow < n) {
            float dv = dinv[grow];
            H[(size_t)grow * 20 + cp] =
                pk2(dv * cbuf[wave][row][2 * cp], dv * cbuf[wave][row][2 * cp + 1]);
        }
    }
}

// Layer-1 fused gather + epilogue. Wave = 4 nodes; quarter (16 lanes) owns one
// node; lane covers 4 channels. Stream = plain src indices, pad-8 (zero row n).
// h1 is PRESCALED by dinv: edge term is a plain add; self term = own row.
__global__ __launch_bounds__(256) void k_conv1(const unsigned long long* __restrict__ rowinfo,
                                               const unsigned* __restrict__ qs,
                                               const float* __restrict__ dinv,
                                               const unsigned* __restrict__ h1,
                                               unsigned* __restrict__ x,
                                               const float* __restrict__ A1,
                                               const float* __restrict__ S1,
                                               const float* __restrict__ k2p,
                                               float* __restrict__ partial, int n) {
    int t = threadIdx.x;
    int lane = t & 63, wave = t >> 6;
    int quarter = lane >> 4, cl = lane & 15;  // channels 4cl..4cl+3
    int node = blockIdx.x * 16 + wave * 4 + quarter;
    float r2 = 0.0f;
    if (node < n) {
        unsigned long long ri = rowinfo[node];
        unsigned beg = (unsigned)ri, pdeg = (unsigned)(ri >> 32);
        float dd = dinv[node];
        float rdd = __builtin_amdgcn_rcpf(dd);
        uint2 hp = *(const uint2*)&h1[(unsigned)node * 32u + 2u * cl];  // dd*h
        float a0 = b2f_lo(hp.x), a1 = b2f_hi(hp.x);   // self term = dd*h
        float a2 = b2f_lo(hp.y), a3 = b2f_hi(hp.y);
        float h0 = a0 * rdd, h1v = a1 * rdd, h2v = a2 * rdd, h3 = a3 * rdd;
        for (unsigned eb = 0; eb < pdeg; eb += 8) {
            uint4 q0 = *(const uint4*)&qs[beg + eb];
            uint4 q1 = *(const uint4*)&qs[beg + eb + 4];
            uint2 p0 = *(const uint2*)&h1[(q0.x << 5) + 2u * cl];
            uint2 p1 = *(const uint2*)&h1[(q0.y << 5) + 2u * cl];
            uint2 p2 = *(const uint2*)&h1[(q0.z << 5) + 2u * cl];
            uint2 p3 = *(const uint2*)&h1[(q0.w << 5) + 2u * cl];
            uint2 p4 = *(const uint2*)&h1[(q1.x << 5) + 2u * cl];
            uint2 p5 = *(const uint2*)&h1[(q1.y << 5) + 2u * cl];
            uint2 p6 = *(const uint2*)&h1[(q1.z << 5) + 2u * cl];
            uint2 p7 = *(const uint2*)&h1[(q1.w << 5) + 2u * cl];
            a0 += b2f_lo(p0.x); a1 += b2f_hi(p0.x);
            a2 += b2f_lo(p0.y); a3 += b2f_hi(p0.y);
            a0 += b2f_lo(p1.x); a1 += b2f_hi(p1.x);
            a2 += b2f_lo(p1.y); a3 += b2f_hi(p1.y);
            a0 += b2f_lo(p2.x); a1 += b2f_hi(p2.x);
            a2 += b2f_lo(p2.y); a3 += b2f_hi(p2.y);
            a0 += b2f_lo(p3.x); a1 += b2f_hi(p3.x);
            a2 += b2f_lo(p3.y); a3 += b2f_hi(p3.y);
            a0 += b2f_lo(p4.x); a1 += b2f_hi(p4.x);
            a2 += b2f_lo(p4.y); a3 += b2f_hi(p4.y);
            a0 += b2f_lo(p5.x); a1 += b2f_hi(p5.x);
            a2 += b2f_lo(p5.y); a3 += b2f_hi(p5.y);
            a0 += b2f_lo(p6.x); a1 += b2f_hi(p6.x);
            a2 += b2f_lo(p6.y); a3 += b2f_hi(p6.y);
            a0 += b2f_lo(p7.x); a1 += b2f_hi(p7.x);
            a2 += b2f_lo(p7.y); a3 += b2f_hi(p7.y);
        }
        float k2 = k2p[0];
        float g0 = dd * a0, g1v = dd * a1, g2v = dd * a2, g3 = dd * a3;  // agg
        float r0 = g0 + (k2 - 1.0f) * h0, r1 = g1v + (k2 - 1.0f) * h1v;
        float r2c = g2v + (k2 - 1.0f) * h2v, r3 = g3 + (k2 - 1.0f) * h3;
        r2 = r0 * r0 + r1 * r1 + r2c * r2c + r3 * r3;
        float4 Ap = *(const float4*)&A1[4 * cl];
        float4 Sp = *(const float4*)&S1[4 * cl];
        float x0 = tanh_fast((g0 + k2 * h0) * Ap.x + Sp.x);
        float x1 = tanh_fast((g1v + k2 * h1v) * Ap.y + Sp.y);
        float x2 = tanh_fast((g2v + k2 * h2v) * Ap.z + Sp.z);
        float x3 = tanh_fast((g3 + k2 * h3) * Ap.w + Sp.w);
        uint2 o;
        o.x = pk2(x0, x1);
        o.y = pk2(x2, x3);
        *(uint2*)&x[(unsigned)node * 32u + 2u * cl] = o;
    }
    for (int off = 32; off; off >>= 1) r2 += __shfl_xor(r2, off, 64);
    __shared__ float red[4];
    if (lane == 0) red[wave] = r2;
    __syncthreads();
    if (t == 0) partial[blockIdx.x] = red[0] + red[1] + red[2] + red[3];
}

// Layer-2 fused gather + BN + tanh + log_softmax at batch nodes. Wave = 2
// nodes (32 lanes each, pair p<20 active); extra last block reduces loss.
__global__ __launch_bounds__(256) void k_conv2(const int* __restrict__ bn,
                                               const unsigned long long* __restrict__ rowinfo,
                                               const unsigned* __restrict__ qs,
                                               const float* __restrict__ dinv,
                                               const unsigned* __restrict__ h2,
                                               const float* __restrict__ A2,
                                               const float* __restrict__ S2,
                                               const float* __restrict__ k2p,
                                               const float* __restrict__ partial,
                                               int nparts, float inv_cnt,
                                               float* __restrict__ out, int nb) {
    int lane = threadIdx.x & 63, wave = threadIdx.x >> 6;
    if (blockIdx.x == gridDim.x - 1) {
        float s = 0.f;
        for (int i = threadIdx.x; i < nparts; i += 256) s += partial[i];
        for (int off = 32; off; off >>= 1) s += __shfl_xor(s, off, 64);
        __shared__ float red[4];
        if (lane == 0) red[wave] = s;
        __syncthreads();
        if (threadIdx.x == 0)
            out[(size_t)nb * 40] = (red[0] + red[1] + red[2] + red[3]) * inv_cnt;
        return;
    }
    int half = lane >> 5, p32 = lane & 31;
    unsigned p = (unsigned)min(p32, 19);
    int wid = blockIdx.x * 8 + wave * 2 + half;
    if (wid >= nb) return;
    int node = bn[wid];
    unsigned long long ri = rowinfo[node];
    unsigned beg = (unsigned)ri, pdeg = (unsigned)(ri >> 32);
    float dd = dinv[node];
    float rdd = __builtin_amdgcn_rcpf(dd);
    unsigned hp = h2[(unsigned)node * 20u + p];  // dd*h
    float ax = b2f_lo(hp), ay = b2f_hi(hp);      // self term
    float hx = ax * rdd, hy = ay * rdd;
    for (unsigned eb = 0; eb < pdeg; eb += 8) {
        uint4 q0 = *(const uint4*)&qs[beg + eb];
        uint4 q1 = *(const uint4*)&qs[beg + eb + 4];
        unsigned pv0 = h2[q0.x * 20u + p];
        unsigned pv1 = h2[q0.y * 20u + p];
        unsigned pv2 = h2[q0.z * 20u + p];
        unsigned pv3 = h2[q0.w * 20u + p];
        unsigned pv4 = h2[q1.x * 20u + p];
        unsigned pv5 = h2[q1.y * 20u + p];
        unsigned pv6 = h2[q1.z * 20u + p];
        unsigned pv7 = h2[q1.w * 20u + p];
        ax += b2f_lo(pv0); ay += b2f_hi(pv0);
        ax += b2f_lo(pv1); ay += b2f_hi(pv1);
        ax += b2f_lo(pv2); ay += b2f_hi(pv2);
        ax += b2f_lo(pv3); ay += b2f_hi(pv3);
        ax += b2f_lo(pv4); ay += b2f_hi(pv4);
        ax += b2f_lo(pv5); ay += b2f_hi(pv5);
        ax += b2f_lo(pv6); ay += b2f_hi(pv6);
        ax += b2f_lo(pv7); ay += b2f_hi(pv7);
    }
    float k2 = k2p[0];
    float2 Ap = *(const float2*)&A2[2 * p];
    float2 Sp = *(const float2*)&S2[2 * p];
    float tx = tanh_fast((dd * ax + k2 * hx) * Ap.x + Sp.x);
    float ty = tanh_fast((dd * ay + k2 * hy) * Ap.y + Sp.y);
    bool act = (p32 < 20);
    float mx = act ? fmaxf(tx, ty) : -INFINITY;
    for (int off = 16; off; off >>= 1) mx = fmaxf(mx, __shfl_xor(mx, off, 32));
    float es = act ? (__expf(tx - mx) + __expf(ty - mx)) : 0.f;
    for (int off = 16; off; off >>= 1) es += __shfl_xor(es, off, 32);
    if (act) {
        float ls = mx + __logf(es);
        float2 o = make_float2(tx - ls, ty - ls);
        *(float2*)&out[(size_t)wid * 40 + 2 * p] = o;
    }
}

extern "C" void kernel_launch(void* const* d_in, const int* in_sizes, int n_in,
                              void* d_out, int out_size, void* d_ws, size_t ws_size,
                              hipStream_t stream) {
    const float* features = (const float*)d_in[0];
    const int* edge_index = (const int*)d_in[1];
    const int* batch_nodes = (const int*)d_in[2];
    const float* W1 = (const float*)d_in[3];
    const float* b1 = (const float*)d_in[4];
    const float* k2_1 = (const float*)d_in[5];
    const float* W2 = (const float*)d_in[6];
    const float* b2 = (const float*)d_in[7];
    const float* k2_2 = (const float*)d_in[8];
    const float* g1 = (const float*)d_in[9];
    const float* be1 = (const float*)d_in[10];
    const float* m1 = (const float*)d_in[11];
    const float* v1 = (const float*)d_in[12];
    const float* g2 = (const float*)d_in[13];
    const float* be2 = (const float*)d_in[14];
    const float* m2 = (const float*)d_in[15];
    const float* v2 = (const float*)d_in[16];

    const int N = in_sizes[0] / 128;
    const int E = in_sizes[1] / 2;
    const int NB = in_sizes[2];
    const int* src = edge_index;
    const int* dst = edge_index + E;
    const int NPART = (N + 15) / 16;   // conv1 grid (4 nodes/wave)
    const int NBKT = (N + 255) >> 8;   // <= 512
    const int PBLK = 256;

    unsigned* ws = (unsigned*)d_ws;
    auto align64 = [](size_t o) { return (o + 63) & ~(size_t)63; };
    size_t o = 0;
    unsigned long long* rowinfo = (unsigned long long*)(ws + o); o = align64(o + 2 * (size_t)N);
    float* dinv = (float*)(ws + o);       o = align64(o + N);
    float* A1 = (float*)(ws + o);         o = align64(o + 64);
    float* S1 = (float*)(ws + o);         o = align64(o + 64);
    float* A2 = (float*)(ws + o);         o = align64(o + 64);
    float* S2 = (float*)(ws + o);         o = align64(o + 64);
    unsigned* bcnt = ws + o;              o = align64(o + NB_BKT);
    float* partial = (float*)(ws + o);    o = align64(o + NPART);
    unsigned* qs = ws + o;                o = align64(o + (size_t)NB_BKT * PSTRIDE);
    unsigned* h1 = ws + o;                o = align64(o + (size_t)(N + 1) * 32);
    unsigned* x = ws + o;                 o = align64(o + (size_t)N * 32);
    unsigned* h2 = ws + o;                o = align64(o + (size_t)(N + 1) * 20);
    unsigned* part = ws + o;              o = align64(o + (size_t)NB_BKT * RCAP);

    hipMemsetAsync(bcnt, 0, NB_BKT * sizeof(unsigned), stream);
    k_part<<<PBLK, 256, 0, stream>>>(src, dst, E, bcnt, part);
    k_build<<<NBKT, 256, 0, stream>>>(part, bcnt, rowinfo, dinv, qs, N, b1, g1,
                                      be1, m1, v1, b2, g2, be2, m2, v2, A1, S1,
                                      A2, S2, h1, h2);
    k_gemm1<<<(N + 63) / 64, 256, 0, stream>>>(features, W1, dinv, h1, N);
    k_conv1<<<NPART, 256, 0, stream>>>(rowinfo, qs, dinv, h1, x, A1, S1, k2_1,
                                       partial, N);
    k_gemm2<<<(N + 63) / 64, 256, 0, stream>>>((const unsigned short*)x, W2, dinv,
                                               h2, N);
    k_conv2<<<(NB + 7) / 8 + 1, 256, 0, stream>>>(batch_nodes, rowinfo, qs, dinv, h2,
                                                  A2, S2, k2_2, partial, NPART,
                                                  1.0f / ((float)N * 64.0f),
                                                  (float*)d_out, NB);
}

// Round 12
// 214.136 us; speedup vs baseline: 3.5344x; 3.5344x over previous
//
#include <hip/hip_runtime.h>
#include <math.h>

// ---------------------------------------------------------------------------
// HelmholtzGCN forward. R12 = R10 (revert R11's single-pass k_part: 1.6M
// value-returning atomics on 512 hot addresses serialized at L2 — 556 µs).
// Two-pass k_part: per-block LDS histogram + ONE global reservation per
// bucket per block, then LDS-cursor scatter. 219.7 µs configuration.
//   memset(bcnt) -> k_part -> k_build(+BN tables, zero rows) -> k_gemm1 ->
//   k_conv1 -> k_gemm2 -> k_conv2(+loss block)
// h1/h2 are dinv-prescaled in the GEMM epilogues; edge stream = plain src
// index (pad = zero-row N); convs: 4 nodes/wave, 4ch/lane, pad-8 unroll-8.
// ---------------------------------------------------------------------------

#define BN_EPS 1e-5f
#define NB_BKT 512
#define RCAP 4608      // raw per-bucket capacity (mean 4096, ~8 sigma)
#define PSTRIDE 6400   // RCAP + 256*7 max pad (pad-to-8)

typedef __attribute__((ext_vector_type(8))) short bf16x8;
typedef __attribute__((ext_vector_type(4))) float f32x4;

__device__ inline unsigned short f2b(float f) {
    unsigned u = __float_as_uint(f);
    unsigned r = (u + 0x7fffu + ((u >> 16) & 1u)) >> 16;
    return (unsigned short)r;
}
__device__ inline float b2f_lo(unsigned u) { return __uint_as_float(u << 16); }
__device__ inline float b2f_hi(unsigned u) { return __uint_as_float(u & 0xffff0000u); }
__device__ inline unsigned pk2(float a, float b) {
    return (unsigned)f2b(a) | ((unsigned)f2b(b) << 16);
}
__device__ inline float tanh_fast(float x) {
    float e = __expf(2.0f * x);
    return 1.0f - 2.0f * __builtin_amdgcn_rcpf(e + 1.0f);
}

// partition edges into fixed-stride buckets; packed u32 = (dst&255)<<24 | src
// Two-pass: LDS hist -> one global atomic per (block,bucket) -> LDS cursors.
__global__ __launch_bounds__(256) void k_part(const int* __restrict__ src,
                                              const int* __restrict__ dst, int e,
                                              unsigned* __restrict__ bcnt,
                                              unsigned* __restrict__ part, int nblk) {
    __shared__ unsigned h[NB_BKT];
    __shared__ unsigned gbase[NB_BKT];
    __shared__ unsigned cur[NB_BKT];
    int chunk = ((e + nblk - 1) / nblk + 3) & ~3;
    int c0 = blockIdx.x * chunk;
    int c1 = min(c0 + chunk, e);
    if (c0 >= e) return;
    for (int i = threadIdx.x; i < NB_BKT; i += 256) h[i] = 0;
    __syncthreads();
    for (int i = c0 + threadIdx.x * 4; i < c1; i += 1024) {
        if (i + 3 < c1) {
            int4 d = *(const int4*)&dst[i];
            atomicAdd(&h[(unsigned)d.x >> 8], 1u);
            atomicAdd(&h[(unsigned)d.y >> 8], 1u);
            atomicAdd(&h[(unsigned)d.z >> 8], 1u);
            atomicAdd(&h[(unsigned)d.w >> 8], 1u);
        } else {
            for (int j = i; j < c1; ++j) atomicAdd(&h[(unsigned)dst[j] >> 8], 1u);
        }
    }
    __syncthreads();
    for (int i = threadIdx.x; i < NB_BKT; i += 256) {
        unsigned c = h[i];
        gbase[i] = c ? (i * RCAP + atomicAdd(&bcnt[i], c)) : 0u;
        cur[i] = 0;
    }
    __syncthreads();
    for (int i = c0 + threadIdx.x * 4; i < c1; i += 1024) {
        if (i + 3 < c1) {
            int4 s = *(const int4*)&src[i];
            int4 d = *(const int4*)&dst[i];
            unsigned b0 = (unsigned)d.x >> 8, b1 = (unsigned)d.y >> 8;
            unsigned b2 = (unsigned)d.z >> 8, b3 = (unsigned)d.w >> 8;
            unsigned p0 = gbase[b0] + atomicAdd(&cur[b0], 1u);
            unsigned p1 = gbase[b1] + atomicAdd(&cur[b1], 1u);
            unsigned p2 = gbase[b2] + atomicAdd(&cur[b2], 1u);
            unsigned p3 = gbase[b3] + atomicAdd(&cur[b3], 1u);
            if (p0 < (b0 + 1) * RCAP) part[p0] = (((unsigned)d.x & 255u) << 24) | (unsigned)s.x;
            if (p1 < (b1 + 1) * RCAP) part[p1] = (((unsigned)d.y & 255u) << 24) | (unsigned)s.y;
            if (p2 < (b2 + 1) * RCAP) part[p2] = (((unsigned)d.z & 255u) << 24) | (unsigned)s.z;
            if (p3 < (b3 + 1) * RCAP) part[p3] = (((unsigned)d.w & 255u) << 24) | (unsigned)s.w;
        } else {
            for (int j = i; j < c1; ++j) {
                unsigned b = (unsigned)dst[j] >> 8;
                unsigned p = gbase[b] + atomicAdd(&cur[b], 1u);
                if (p < (b + 1) * RCAP)
                    part[p] = (((unsigned)dst[j] & 255u) << 24) | (unsigned)src[j];
            }
        }
    }
}

// Fused deg+scatter: per-bucket hist -> pad-8 scan -> rowinfo/dinv -> scatter
// plain src indices (pad = n, the zero row). Block 0: BN tables + zero rows.
__global__ __launch_bounds__(256) void k_build(const unsigned* __restrict__ part,
                                               const unsigned* __restrict__ bcnt,
                                               unsigned long long* __restrict__ rowinfo,
                                               float* __restrict__ dinv,
                                               unsigned* __restrict__ qs, int n,
                                               const float* __restrict__ b1,
                                               const float* __restrict__ g1,
                                               const float* __restrict__ be1,
                                               const float* __restrict__ m1,
                                               const float* __restrict__ v1,
                                               const float* __restrict__ b2p,
                                               const float* __restrict__ g2,
                                               const float* __restrict__ be2,
                                               const float* __restrict__ m2,
                                               const float* __restrict__ v2,
                                               float* __restrict__ A1,
                                               float* __restrict__ S1,
                                               float* __restrict__ A2,
                                               float* __restrict__ S2,
                                               unsigned* __restrict__ h1,
                                               unsigned* __restrict__ h2) {
    __shared__ unsigned hist[256];
    __shared__ unsigned sc[256];
    __shared__ unsigned cur[256];
    __shared__ unsigned pend[256];
    int b = blockIdx.x;
    int t = threadIdx.x;
    if (b == 0) {  // BN tables + zero pad rows (independent of shared state)
        if (t < 64) {
            float a = g1[t] * rsqrtf(v1[t] + BN_EPS);
            A1[t] = a;
            S1[t] = (b1[t] - m1[t]) * a + be1[t];
        } else if (t < 104) {
            int cc = t - 64;
            float a = g2[cc] * rsqrtf(v2[cc] + BN_EPS);
            A2[cc] = a;
            S2[cc] = (b2p[cc] - m2[cc]) * a + be2[cc];
        } else if (t < 136) {
            h1[(size_t)n * 32u + (t - 104)] = 0u;
        } else if (t < 156) {
            h2[(size_t)n * 20u + (t - 136)] = 0u;
        }
    }
    int cnt = (int)min(bcnt[b], (unsigned)RCAP);
    unsigned base = b * RCAP;
    int dst0 = b << 8;
    int nloc = min(256, n - dst0);
    hist[t] = 0;
    __syncthreads();
    for (int i = t; i < cnt; i += 256) atomicAdd(&hist[part[base + i] >> 24], 1u);
    __syncthreads();
    unsigned c = hist[t];
    unsigned pcnt = (t < nloc) ? ((c + 7u) & ~7u) : 0u;
    sc[t] = pcnt;
    __syncthreads();
    for (int off = 1; off < 256; off <<= 1) {
        unsigned a = (t >= off) ? sc[t - off] : 0u;
        __syncthreads();
        sc[t] += a;
        __syncthreads();
    }
    unsigned beg = (unsigned)b * PSTRIDE + (sc[t] - pcnt);
    if (t < nloc) {
        rowinfo[dst0 + t] = (unsigned long long)beg | ((unsigned long long)pcnt << 32);
        dinv[dst0 + t] = rsqrtf((float)(c + 1u));
    }
    cur[t] = beg;
    pend[t] = beg + pcnt;
    __syncthreads();
    for (int i = t; i < cnt; i += 256) {
        unsigned p = part[base + i];
        unsigned pos = atomicAdd(&cur[p >> 24], 1u);
        qs[pos] = p & 0xFFFFFFu;
    }
    __syncthreads();
    for (unsigned pos = cur[t]; pos < pend[t]; ++pos) qs[pos] = (unsigned)n;
}

// H1'[n+1,32 u32 pairs](bf16) = dinv[row] * (X[n,128](f32) @ W[128,64]) via MFMA.
__global__ __launch_bounds__(256) void k_gemm1(const float* __restrict__ X,
                                               const float* __restrict__ W,
                                               const float* __restrict__ dinv,
                                               unsigned* __restrict__ H, int n) {
    __shared__ short wb[4][4][64][8];
    __shared__ float cbuf[4][16][65];
    int t = threadIdx.x;
    for (int s = t; s < 1024; s += 256) {
        int l = s & 63, nt = (s >> 6) & 3, kt = s >> 8;
        int kbase = kt * 32 + ((l >> 4) << 3);
        int nn = nt * 16 + (l & 15);
        bf16x8 v;
#pragma unroll
        for (int j = 0; j < 8; ++j) v[j] = (short)f2b(W[(kbase + j) * 64 + nn]);
        *(bf16x8*)&wb[kt][nt][l][0] = v;
    }
    __syncthreads();
    int lane = t & 63, wave = t >> 6;
    int quad = lane >> 4, m = lane & 15;
    int r0 = blockIdx.x * 64 + wave * 16;
    f32x4 acc[4];
#pragma unroll
    for (int i = 0; i < 4; ++i) acc[i] = (f32x4){0.f, 0.f, 0.f, 0.f};
    int rr = min(r0 + m, n - 1);
    const float* xrow = X + (size_t)rr * 128;
#pragma unroll
    for (int kt = 0; kt < 4; ++kt) {
        int kb = kt * 32 + quad * 8;
        float4 x0 = *(const float4*)&xrow[kb];
        float4 x1 = *(const float4*)&xrow[kb + 4];
        bf16x8 af;
        af[0] = (short)f2b(x0.x); af[1] = (short)f2b(x0.y);
        af[2] = (short)f2b(x0.z); af[3] = (short)f2b(x0.w);
        af[4] = (short)f2b(x1.x); af[5] = (short)f2b(x1.y);
        af[6] = (short)f2b(x1.z); af[7] = (short)f2b(x1.w);
#pragma unroll
        for (int nt = 0; nt < 4; ++nt) {
            bf16x8 bf = *(bf16x8*)&wb[kt][nt][lane][0];
            acc[nt] = __builtin_amdgcn_mfma_f32_16x16x32_bf16(af, bf, acc[nt], 0, 0, 0);
        }
    }
#pragma unroll
    for (int nt = 0; nt < 4; ++nt)
#pragma unroll
        for (int r = 0; r < 4; ++r)
            cbuf[wave][quad * 4 + r][nt * 16 + m] = acc[nt][r];
    __syncthreads();
#pragma unroll
    for (int i = 0; i < 8; ++i) {
        int f = i * 64 + lane;
        int row = f >> 5, cp = f & 31;
        int grow = r0 + row;
        if (grow < n) {
            float dv = dinv[grow];
            H[(size_t)grow * 32 + cp] =
                pk2(dv * cbuf[wave][row][2 * cp], dv * cbuf[wave][row][2 * cp + 1]);
        }
    }
}

// H2'[n+1,20 u32 pairs](bf16) = dinv[row] * (Xb[n,64](bf16) @ W2[64,40]) via MFMA.
__global__ __launch_bounds__(256) void k_gemm2(const unsigned short* __restrict__ X,
                                               const float* __restrict__ W,
                                               const float* __restrict__ dinv,
                                               unsigned* __restrict__ H, int n) {
    __shared__ short wb[2][3][64][8];
    __shared__ float cbuf[4][16][49];
    int t = threadIdx.x;
    for (int s = t; s < 384; s += 256) {
        int l = s & 63, nt = (s >> 6) % 3, kt = s / 192;
        int kbase = kt * 32 + ((l >> 4) << 3);
        int c = nt * 16 + (l & 15);
        bf16x8 v;
#pragma unroll
        for (int j = 0; j < 8; ++j)
            v[j] = (c < 40) ? (short)f2b(W[(kbase + j) * 40 + c]) : (short)0;
        *(bf16x8*)&wb[kt][nt][l][0] = v;
    }
    __syncthreads();
    int lane = t & 63, wave = t >> 6;
    int quad = lane >> 4, m = lane & 15;
    int r0 = blockIdx.x * 64 + wave * 16;
    f32x4 acc[3];
#pragma unroll
    for (int i = 0; i < 3; ++i) acc[i] = (f32x4){0.f, 0.f, 0.f, 0.f};
    int rr = min(r0 + m, n - 1);
    const unsigned short* xrow = X + (size_t)rr * 64;
#pragma unroll
    for (int kt = 0; kt < 2; ++kt) {
        bf16x8 af = *(const bf16x8*)&xrow[kt * 32 + quad * 8];
#pragma unroll
        for (int nt = 0; nt < 3; ++nt) {
            bf16x8 bf = *(bf16x8*)&wb[kt][nt][lane][0];
            acc[nt] = __builtin_amdgcn_mfma_f32_16x16x32_bf16(af, bf, acc[nt], 0, 0, 0);
        }
    }
#pragma unroll
    for (int nt = 0; nt < 3; ++nt)
#pragma unroll
        for (int r = 0; r < 4; ++r)
            cbuf[wave][quad * 4 + r][nt * 16 + m] = acc[nt][r];
    __syncthreads();
#pragma unroll
    for (int i = 0; i < 5; ++i) {
        int f = i * 64 + lane;
        int row = f / 20, cp = f % 20;
        int grow = r0 + row;
        if (grow < n) {
            float dv = dinv[grow];
            H[(size_t)grow * 20 + cp] =
                pk2(dv * cbuf[wave][row][2 * cp], dv * cbuf[wave][row][2 * cp + 1]);
        }
    }
}

// Layer-1 fused gather + epilogue. Wave = 4 nodes; quarter (16 lanes) owns one
// node; lane covers 4 channels. Stream = plain src indices, pad-8 (zero row n).
// h1 is PRESCALED by dinv: edge term is a plain add; self term = own row.
__global__ __launch_bounds__(256) void k_conv1(const unsigned long long* __restrict__ rowinfo,
                                               const unsigned* __restrict__ qs,
                                               const float* __restrict__ dinv,
                                               const unsigned* __restrict__ h1,
                                               unsigned* __restrict__ x,
                                               const float* __restrict__ A1,
                                               const float* __restrict__ S1,
                                               const float* __restrict__ k2p,
                                               float* __restrict__ partial, int n) {
    int t = threadIdx.x;
    int lane = t & 63, wave = t >> 6;
    int quarter = lane >> 4, cl = lane & 15;  // channels 4cl..4cl+3
    int node = blockIdx.x * 16 + wave * 4 + quarter;
    float r2 = 0.0f;
    if (node < n) {
        unsigned long long ri = rowinfo[node];
        unsigned beg = (unsigned)ri, pdeg = (unsigned)(ri >> 32);
        float dd = dinv[node];
        float rdd = __builtin_amdgcn_rcpf(dd);
        uint2 hp = *(const uint2*)&h1[(unsigned)node * 32u + 2u * cl];  // dd*h
        float a0 = b2f_lo(hp.x), a1 = b2f_hi(hp.x);   // self term = dd*h
        float a2 = b2f_lo(hp.y), a3 = b2f_hi(hp.y);
        float h0 = a0 * rdd, h1v = a1 * rdd, h2v = a2 * rdd, h3 = a3 * rdd;
        for (unsigned eb = 0; eb < pdeg; eb += 8) {
            uint4 q0 = *(const uint4*)&qs[beg + eb];
            uint4 q1 = *(const uint4*)&qs[beg + eb + 4];
            uint2 p0 = *(const uint2*)&h1[(q0.x << 5) + 2u * cl];
            uint2 p1 = *(const uint2*)&h1[(q0.y << 5) + 2u * cl];
            uint2 p2 = *(const uint2*)&h1[(q0.z << 5) + 2u * cl];
            uint2 p3 = *(const uint2*)&h1[(q0.w << 5) + 2u * cl];
            uint2 p4 = *(const uint2*)&h1[(q1.x << 5) + 2u * cl];
            uint2 p5 = *(const uint2*)&h1[(q1.y << 5) + 2u * cl];
            uint2 p6 = *(const uint2*)&h1[(q1.z << 5) + 2u * cl];
            uint2 p7 = *(const uint2*)&h1[(q1.w << 5) + 2u * cl];
            a0 += b2f_lo(p0.x); a1 += b2f_hi(p0.x);
            a2 += b2f_lo(p0.y); a3 += b2f_hi(p0.y);
            a0 += b2f_lo(p1.x); a1 += b2f_hi(p1.x);
            a2 += b2f_lo(p1.y); a3 += b2f_hi(p1.y);
            a0 += b2f_lo(p2.x); a1 += b2f_hi(p2.x);
            a2 += b2f_lo(p2.y); a3 += b2f_hi(p2.y);
            a0 += b2f_lo(p3.x); a1 += b2f_hi(p3.x);
            a2 += b2f_lo(p3.y); a3 += b2f_hi(p3.y);
            a0 += b2f_lo(p4.x); a1 += b2f_hi(p4.x);
            a2 += b2f_lo(p4.y); a3 += b2f_hi(p4.y);
            a0 += b2f_lo(p5.x); a1 += b2f_hi(p5.x);
            a2 += b2f_lo(p5.y); a3 += b2f_hi(p5.y);
            a0 += b2f_lo(p6.x); a1 += b2f_hi(p6.x);
            a2 += b2f_lo(p6.y); a3 += b2f_hi(p6.y);
            a0 += b2f_lo(p7.x); a1 += b2f_hi(p7.x);
            a2 += b2f_lo(p7.y); a3 += b2f_hi(p7.y);
        }
        float k2 = k2p[0];
        float g0 = dd * a0, g1v = dd * a1, g2v = dd * a2, g3 = dd * a3;  // agg
        float r0 = g0 + (k2 - 1.0f) * h0, r1 = g1v + (k2 - 1.0f) * h1v;
        float r2c = g2v + (k2 - 1.0f) * h2v, r3 = g3 + (k2 - 1.0f) * h3;
        r2 = r0 * r0 + r1 * r1 + r2c * r2c + r3 * r3;
        float4 Ap = *(const float4*)&A1[4 * cl];
        float4 Sp = *(const float4*)&S1[4 * cl];
        float x0 = tanh_fast((g0 + k2 * h0) * Ap.x + Sp.x);
        float x1 = tanh_fast((g1v + k2 * h1v) * Ap.y + Sp.y);
        float x2 = tanh_fast((g2v + k2 * h2v) * Ap.z + Sp.z);
        float x3 = tanh_fast((g3 + k2 * h3) * Ap.w + Sp.w);
        uint2 o;
        o.x = pk2(x0, x1);
        o.y = pk2(x2, x3);
        *(uint2*)&x[(unsigned)node * 32u + 2u * cl] = o;
    }
    for (int off = 32; off; off >>= 1) r2 += __shfl_xor(r2, off, 64);
    __shared__ float red[4];
    if (lane == 0) red[wave] = r2;
    __syncthreads();
    if (t == 0) partial[blockIdx.x] = red[0] + red[1] + red[2] + red[3];
}

// Layer-2 fused gather + BN + tanh + log_softmax at batch nodes. Wave = 2
// nodes (32 lanes each, pair p<20 active); extra last block reduces loss.
__global__ __launch_bounds__(256) void k_conv2(const int* __restrict__ bn,
                                               const unsigned long long* __restrict__ rowinfo,
                                               const unsigned* __restrict__ qs,
                                               const float* __restrict__ dinv,
                                               const unsigned* __restrict__ h2,
                                               const float* __restrict__ A2,
                                               const float* __restrict__ S2,
                                               const float* __restrict__ k2p,
                                               const float* __restrict__ partial,
                                               int nparts, float inv_cnt,
                                               float* __restrict__ out, int nb) {
    int lane = threadIdx.x & 63, wave = threadIdx.x >> 6;
    if (blockIdx.x == gridDim.x - 1) {
        float s = 0.f;
        for (int i = threadIdx.x; i < nparts; i += 256) s += partial[i];
        for (int off = 32; off; off >>= 1) s += __shfl_xor(s, off, 64);
        __shared__ float red[4];
        if (lane == 0) red[wave] = s;
        __syncthreads();
        if (threadIdx.x == 0)
            out[(size_t)nb * 40] = (red[0] + red[1] + red[2] + red[3]) * inv_cnt;
        return;
    }
    int half = lane >> 5, p32 = lane & 31;
    unsigned p = (unsigned)min(p32, 19);
    int wid = blockIdx.x * 8 + wave * 2 + half;
    if (wid >= nb) return;
    int node = bn[wid];
    unsigned long long ri = rowinfo[node];
    unsigned beg = (unsigned)ri, pdeg = (unsigned)(ri >> 32);
    float dd = dinv[node];
    float rdd = __builtin_amdgcn_rcpf(dd);
    unsigned hp = h2[(unsigned)node * 20u + p];  // dd*h
    float ax = b2f_lo(hp), ay = b2f_hi(hp);      // self term
    float hx = ax * rdd, hy = ay * rdd;
    for (unsigned eb = 0; eb < pdeg; eb += 8) {
        uint4 q0 = *(const uint4*)&qs[beg + eb];
        uint4 q1 = *(const uint4*)&qs[beg + eb + 4];
        unsigned pv0 = h2[q0.x * 20u + p];
        unsigned pv1 = h2[q0.y * 20u + p];
        unsigned pv2 = h2[q0.z * 20u + p];
        unsigned pv3 = h2[q0.w * 20u + p];
        unsigned pv4 = h2[q1.x * 20u + p];
        unsigned pv5 = h2[q1.y * 20u + p];
        unsigned pv6 = h2[q1.z * 20u + p];
        unsigned pv7 = h2[q1.w * 20u + p];
        ax += b2f_lo(pv0); ay += b2f_hi(pv0);
        ax += b2f_lo(pv1); ay += b2f_hi(pv1);
        ax += b2f_lo(pv2); ay += b2f_hi(pv2);
        ax += b2f_lo(pv3); ay += b2f_hi(pv3);
        ax += b2f_lo(pv4); ay += b2f_hi(pv4);
        ax += b2f_lo(pv5); ay += b2f_hi(pv5);
        ax += b2f_lo(pv6); ay += b2f_hi(pv6);
        ax += b2f_lo(pv7); ay += b2f_hi(pv7);
    }
    float k2 = k2p[0];
    float2 Ap = *(const float2*)&A2[2 * p];
    float2 Sp = *(const float2*)&S2[2 * p];
    float tx = tanh_fast((dd * ax + k2 * hx) * Ap.x + Sp.x);
    float ty = tanh_fast((dd * ay + k2 * hy) * Ap.y + Sp.y);
    bool act = (p32 < 20);
    float mx = act ? fmaxf(tx, ty) : -INFINITY;
    for (int off = 16; off; off >>= 1) mx = fmaxf(mx, __shfl_xor(mx, off, 32));
    float es = act ? (__expf(tx - mx) + __expf(ty - mx)) : 0.f;
    for (int off = 16; off; off >>= 1) es += __shfl_xor(es, off, 32);
    if (act) {
        float ls = mx + __logf(es);
        float2 o = make_float2(tx - ls, ty - ls);
        *(float2*)&out[(size_t)wid * 40 + 2 * p] = o;
    }
}

extern "C" void kernel_launch(void* const* d_in, const int* in_sizes, int n_in,
                              void* d_out, int out_size, void* d_ws, size_t ws_size,
                              hipStream_t stream) {
    const float* features = (const float*)d_in[0];
    const int* edge_index = (const int*)d_in[1];
    const int* batch_nodes = (const int*)d_in[2];
    const float* W1 = (const float*)d_in[3];
    const float* b1 = (const float*)d_in[4];
    const float* k2_1 = (const float*)d_in[5];
    const float* W2 = (const float*)d_in[6];
    const float* b2 = (const float*)d_in[7];
    const float* k2_2 = (const float*)d_in[8];
    const float* g1 = (const float*)d_in[9];
    const float* be1 = (const float*)d_in[10];
    const float* m1 = (const float*)d_in[11];
    const float* v1 = (const float*)d_in[12];
    const float* g2 = (const float*)d_in[13];
    const float* be2 = (const float*)d_in[14];
    const float* m2 = (const float*)d_in[15];
    const float* v2 = (const float*)d_in[16];

    const int N = in_sizes[0] / 128;
    const int E = in_sizes[1] / 2;
    const int NB = in_sizes[2];
    const int* src = edge_index;
    const int* dst = edge_index + E;
    const int NPART = (N + 15) / 16;   // conv1 grid (4 nodes/wave)
    const int NBKT = (N + 255) >> 8;   // <= 512
    const int PBLK = 256;

    unsigned* ws = (unsigned*)d_ws;
    auto align64 = [](size_t o) { return (o + 63) & ~(size_t)63; };
    size_t o = 0;
    unsigned long long* rowinfo = (unsigned long long*)(ws + o); o = align64(o + 2 * (size_t)N);
    float* dinv = (float*)(ws + o);       o = align64(o + N);
    float* A1 = (float*)(ws + o);         o = align64(o + 64);
    float* S1 = (float*)(ws + o);         o = align64(o + 64);
    float* A2 = (float*)(ws + o);         o = align64(o + 64);
    float* S2 = (float*)(ws + o);         o = align64(o + 64);
    unsigned* bcnt = ws + o;              o = align64(o + NB_BKT);
    float* partial = (float*)(ws + o);    o = align64(o + NPART);
    unsigned* qs = ws + o;                o = align64(o + (size_t)NB_BKT * PSTRIDE);
    unsigned* h1 = ws + o;                o = align64(o + (size_t)(N + 1) * 32);
    unsigned* x = ws + o;                 o = align64(o + (size_t)N * 32);
    unsigned* h2 = ws + o;                o = align64(o + (size_t)(N + 1) * 20);
    unsigned* part = ws + o;              o = align64(o + (size_t)NB_BKT * RCAP);

    hipMemsetAsync(bcnt, 0, NB_BKT * sizeof(unsigned), stream);
    k_part<<<PBLK, 256, 0, stream>>>(src, dst, E, bcnt, part, PBLK);
    k_build<<<NBKT, 256, 0, stream>>>(part, bcnt, rowinfo, dinv, qs, N, b1, g1,
                                      be1, m1, v1, b2, g2, be2, m2, v2, A1, S1,
                                      A2, S2, h1, h2);
    k_gemm1<<<(N + 63) / 64, 256, 0, stream>>>(features, W1, dinv, h1, N);
    k_conv1<<<NPART, 256, 0, stream>>>(rowinfo, qs, dinv, h1, x, A1, S1, k2_1,
                                       partial, N);
    k_gemm2<<<(N + 63) / 64, 256, 0, stream>>>((const unsigned short*)x, W2, dinv,
                                               h2, N);
    k_conv2<<<(NB + 7) / 8 + 1, 256, 0, stream>>>(batch_nodes, rowinfo, qs, dinv, h2,
                                                  A2, S2, k2_2, partial, NPART,
                                                  1.0f / ((float)N * 64.0f),
                                                  (float*)d_out, NB);
}